// Round 2
// baseline (148.195 us; speedup 1.0000x reference)
//
#include <hip/hip_runtime.h>

#define BATCH 256
#define NCLS  1019
#define GRID  7
#define NOBJ  16
#define PLANE 49            // GRID*GRID
#define NCH   1024          // 5 + NCLS
#define SLAB  (NCH * PLANE) // 50176 floats per batch
#define NVEC  (SLAB / 4)    // 12544 float4 per batch
#define TPB   1024

__global__ __launch_bounds__(TPB) void yolo_loss_kernel(
    const float* __restrict__ outputs,    // [B, 1024, 7, 7]
    const float* __restrict__ boxes,      // [B, 16, 4]
    const int*   __restrict__ labels,     // [B, 16]  (1..C)
    const int*   __restrict__ coords,     // [B, 16, 2] (x, y)
    const float* __restrict__ obj_matrix, // [B, 49]
    float* __restrict__ out)              // [1]
{
    const int b    = blockIdx.x;
    const int t    = threadIdx.x;
    const int lane = t & 63;
    const int wave = t >> 6;

    __shared__ float s_acc[PLANE];   // sum of exp over class channels, per position
    __shared__ int   s_pos[NOBJ];
    __shared__ int   s_cl[NOBJ];
    __shared__ float s_red;          // block partial sum of the loss

    if (t < PLANE) s_acc[t] = 0.0f;
    if (t == 0)    s_red = 0.0f;
    if (t < NOBJ) {
        int x = coords[(b * NOBJ + t) * 2 + 0];
        int y = coords[(b * NOBJ + t) * 2 + 1];
        s_pos[t] = y * GRID + x;
        s_cl[t]  = labels[b * NOBJ + t] - 1;
    }
    __syncthreads();

    const float*  ob  = outputs + (size_t)b * SLAB;
    const float4* ob4 = (const float4*)ob;

    // ---- coalesced stream of the whole [1024,49] slab; accumulate
    //      exp(logit) per position over the 1019 class channels ----
    for (int vi = t; vi < NVEC; vi += TPB) {
        float4 v = ob4[vi];
        int idx = vi * 4;
        float vals[4] = {v.x, v.y, v.z, v.w};
#pragma unroll
        for (int j = 0; j < 4; ++j) {
            int id = idx + j;
            int c  = id / PLANE;          // strength-reduced const division
            int p  = id - c * PLANE;
            if (c >= 5) atomicAdd(&s_acc[p], __expf(vals[j]));
        }
    }
    __syncthreads();

    // ---------- objectness CE (wave 0) ----------
    if (wave == 0) {
        float l = (lane < PLANE) ? ob[lane] : 0.0f;
        float s = (lane < PLANE) ? __expf(l) : 0.0f;
#pragma unroll
        for (int off = 32; off > 0; off >>= 1)
            s += __shfl_xor(s, off, 64);
        float lse = __logf(s);
        float m = (lane < PLANE) ? obj_matrix[b * PLANE + lane] : 0.0f;
        float contrib = (lane < PLANE) ? -m * (l - lse) : 0.0f;
#pragma unroll
        for (int off = 32; off > 0; off >>= 1)
            contrib += __shfl_xor(contrib, off, 64);
        if (lane == 0) atomicAdd(&s_red, contrib);
    }

    // ---------- bb MSE (wave 1) ----------
    if (wave == 1) {
        int o = lane >> 2, k = lane & 3;   // 64 lanes = 16 objects x 4 coords
        float pred = ob[(size_t)(1 + k) * PLANE + s_pos[o]];
        float tb   = boxes[(b * NOBJ + o) * 4 + k];
        float tgt  = rintf(tb * (10.0f / 448.0f)) * 0.1f;  // round-half-even
        float d    = tgt - pred;
        float sq   = d * d;
#pragma unroll
        for (int off = 32; off > 0; off >>= 1)
            sq += __shfl_xor(sq, off, 64);
        if (lane == 0) atomicAdd(&s_red, sq);
    }

    // ---------- class CE (wave 2, lanes 0..15) ----------
    if (wave == 2 && lane < NOBJ) {
        int   o  = lane;
        float se = s_acc[s_pos[o]];
        float tl = ob[(size_t)(5 + s_cl[o]) * PLANE + s_pos[o]];  // L1/L2 hit
        float ce = __logf(se) - tl;
        atomicAdd(&s_red, ce);
    }

    __syncthreads();
    if (t == 0) atomicAdd(out, s_red * (1.0f / (float)BATCH));
}

extern "C" void kernel_launch(void* const* d_in, const int* in_sizes, int n_in,
                              void* d_out, int out_size, void* d_ws, size_t ws_size,
                              hipStream_t stream) {
    const float* outputs    = (const float*)d_in[0];
    const float* boxes      = (const float*)d_in[1];
    const int*   labels     = (const int*)d_in[2];
    const int*   coords     = (const int*)d_in[3];
    const float* obj_matrix = (const float*)d_in[4];
    float* out = (float*)d_out;

    hipMemsetAsync(out, 0, sizeof(float), stream);
    yolo_loss_kernel<<<BATCH, TPB, 0, stream>>>(outputs, boxes, labels, coords,
                                                obj_matrix, out);
}

// Round 3
// 99.377 us; speedup vs baseline: 1.4912x; 1.4912x over previous
//
#include <hip/hip_runtime.h>

#define BATCH 256
#define NCLS  1019
#define GRID  7
#define NOBJ  16
#define PLANE 49            // GRID*GRID
#define NCH   1024          // 5 + NCLS
#define SLAB  (NCH * PLANE) // 50176 floats per batch
#define TPB   1024
#define NWAVE 16

__global__ __launch_bounds__(TPB) void yolo_loss_kernel(
    const float* __restrict__ outputs,    // [B, 1024, 7, 7]
    const float* __restrict__ boxes,      // [B, 16, 4]
    const int*   __restrict__ labels,     // [B, 16]  (1..C)
    const int*   __restrict__ coords,     // [B, 16, 2] (x, y)
    const float* __restrict__ obj_matrix, // [B, 49]
    float* __restrict__ out)              // [1]
{
    const int b    = blockIdx.x;
    const int t    = threadIdx.x;
    const int lane = t & 63;
    const int w    = t >> 6;

    __shared__ float s_part[NWAVE][64];  // per-wave, per-position sumexp partials
    __shared__ float s_sumexp[64];
    __shared__ int   s_pos[NOBJ];
    __shared__ int   s_cl[NOBJ];
    __shared__ float s_red;

    const float* ob = outputs + (size_t)b * SLAB;

    if (t == 0) s_red = 0.0f;
    if (t < NOBJ) {
        int x = coords[(b * NOBJ + t) * 2 + 0];
        int y = coords[(b * NOBJ + t) * 2 + 1];
        s_pos[t] = y * GRID + x;
        s_cl[t]  = labels[b * NOBJ + t] - 1;
    }
    __syncthreads();

    // ---------- objectness CE (wave 1) ----------
    if (w == 1) {
        float l = (lane < PLANE) ? ob[lane] : 0.0f;
        float s = (lane < PLANE) ? __expf(l) : 0.0f;
#pragma unroll
        for (int off = 32; off > 0; off >>= 1)
            s += __shfl_xor(s, off, 64);
        float lse = __logf(s);
        float m = (lane < PLANE) ? obj_matrix[b * PLANE + lane] : 0.0f;
        float contrib = (lane < PLANE) ? -m * (l - lse) : 0.0f;
#pragma unroll
        for (int off = 32; off > 0; off >>= 1)
            contrib += __shfl_xor(contrib, off, 64);
        if (lane == 0) atomicAdd(&s_red, contrib);
    }

    // ---------- bb MSE (wave 2) ----------
    if (w == 2) {
        int o = lane >> 2, k = lane & 3;   // 64 lanes = 16 objects x 4 coords
        float pred = ob[(size_t)(1 + k) * PLANE + s_pos[o]];
        float tb   = boxes[(b * NOBJ + o) * 4 + k];
        float tgt  = rintf(tb * (10.0f / 448.0f)) * 0.1f;  // round-half-even
        float d    = tgt - pred;
        float sq   = d * d;
#pragma unroll
        for (int off = 32; off > 0; off >>= 1)
            sq += __shfl_xor(sq, off, 64);
        if (lane == 0) atomicAdd(&s_red, sq);
    }

    // ---------- class sumexp: wave w streams channels 5+w, 5+w+16, ... ----------
    // lane p (<49) privately accumulates exp(logit[c][p]); no atomics.
    const int   p = (lane < PLANE) ? lane : 0;       // lanes 49..63 read a valid addr
    const float m = (lane < PLANE) ? 1.0f : 0.0f;    // ...but contribute 0
    float a0 = 0.0f, a1 = 0.0f, a2 = 0.0f, a3 = 0.0f;

    int c = 5 + w;
    for (; c + 48 < NCH; c += 64) {
        float v0 = ob[(c     ) * PLANE + p];
        float v1 = ob[(c + 16) * PLANE + p];
        float v2 = ob[(c + 32) * PLANE + p];
        float v3 = ob[(c + 48) * PLANE + p];
        a0 += m * __expf(v0);
        a1 += m * __expf(v1);
        a2 += m * __expf(v2);
        a3 += m * __expf(v3);
    }
    for (; c < NCH; c += 16)
        a0 += m * __expf(ob[c * PLANE + p]);

    s_part[w][lane] = (a0 + a1) + (a2 + a3);
    __syncthreads();

    // ---------- fold 16 wave partials (wave 0) ----------
    if (w == 0) {
        float s = 0.0f;
#pragma unroll
        for (int i = 0; i < NWAVE; ++i) s += s_part[i][lane];
        s_sumexp[lane] = s;
    }
    __syncthreads();

    // ---------- class CE (wave 0, lanes 0..15) ----------
    if (w == 0 && lane < NOBJ) {
        float se = s_sumexp[s_pos[lane]];
        float tl = ob[(size_t)(5 + s_cl[lane]) * PLANE + s_pos[lane]];  // cache hit
        float ce = __logf(se) - tl;
        atomicAdd(&s_red, ce);
    }
    __syncthreads();

    if (t == 0) atomicAdd(out, s_red * (1.0f / (float)BATCH));
}

extern "C" void kernel_launch(void* const* d_in, const int* in_sizes, int n_in,
                              void* d_out, int out_size, void* d_ws, size_t ws_size,
                              hipStream_t stream) {
    const float* outputs    = (const float*)d_in[0];
    const float* boxes      = (const float*)d_in[1];
    const int*   labels     = (const int*)d_in[2];
    const int*   coords     = (const int*)d_in[3];
    const float* obj_matrix = (const float*)d_in[4];
    float* out = (float*)d_out;

    hipMemsetAsync(out, 0, sizeof(float), stream);
    yolo_loss_kernel<<<BATCH, TPB, 0, stream>>>(outputs, boxes, labels, coords,
                                                obj_matrix, out);
}

// Round 4
// 93.203 us; speedup vs baseline: 1.5900x; 1.0662x over previous
//
#include <hip/hip_runtime.h>

#define BATCH 256
#define NCLS  1019
#define GRID  7
#define NOBJ  16
#define PLANE 49              // GRID*GRID
#define NCH   1024            // 5 + NCLS
#define SLAB  (NCH * PLANE)   // 50176 floats per batch = 196*256
#define TPB   1024
#define NWAVE 16
#define NGRP  256             // SLAB / 196 groups of 49 float4

__global__ __launch_bounds__(TPB) void yolo_loss_kernel(
    const float* __restrict__ outputs,    // [B, 1024, 7, 7]
    const float* __restrict__ boxes,      // [B, 16, 4]
    const int*   __restrict__ labels,     // [B, 16]  (1..C)
    const int*   __restrict__ coords,     // [B, 16, 2] (x, y)
    const float* __restrict__ obj_matrix, // [B, 49]
    float* __restrict__ out)              // [1]
{
    const int b    = blockIdx.x;
    const int t    = threadIdx.x;
    const int lane = t & 63;
    const int w    = t >> 6;

    __shared__ float s_slot[NWAVE][4 * PLANE];  // 196 slot-partials per wave
    __shared__ float s_sum[PLANE];              // final per-position sumexp (class rows)
    __shared__ int   s_pos[NOBJ];
    __shared__ int   s_cl[NOBJ];
    __shared__ float s_red;

    const float*  ob  = outputs + (size_t)b * SLAB;
    const float4* ob4 = (const float4*)ob;      // slab base is 16B-aligned

    if (t == 0) s_red = 0.0f;
    if (t < NOBJ) {
        int x = coords[(b * NOBJ + t) * 2 + 0];
        int y = coords[(b * NOBJ + t) * 2 + 1];
        s_pos[t] = y * GRID + x;
        s_cl[t]  = labels[b * NOBJ + t] - 1;
    }
    __syncthreads();

    // ---------- objectness CE (wave 1) ----------
    if (w == 1) {
        float l = (lane < PLANE) ? ob[lane] : 0.0f;
        float s = (lane < PLANE) ? __expf(l) : 0.0f;
#pragma unroll
        for (int off = 32; off > 0; off >>= 1)
            s += __shfl_xor(s, off, 64);
        float lse = __logf(s);
        float mm = (lane < PLANE) ? obj_matrix[b * PLANE + lane] : 0.0f;
        float contrib = (lane < PLANE) ? -mm * (l - lse) : 0.0f;
#pragma unroll
        for (int off = 32; off > 0; off >>= 1)
            contrib += __shfl_xor(contrib, off, 64);
        if (lane == 0) atomicAdd(&s_red, contrib);
    }

    // ---------- bb MSE (wave 2) ----------
    if (w == 2) {
        int o = lane >> 2, k = lane & 3;   // 64 lanes = 16 objects x 4 coords
        float pred = ob[(size_t)(1 + k) * PLANE + s_pos[o]];
        float tb   = boxes[(b * NOBJ + o) * 4 + k];
        float tgt  = rintf(tb * (10.0f / 448.0f)) * 0.1f;  // round-half-even
        float d    = tgt - pred;
        float sq   = d * d;
#pragma unroll
        for (int off = 32; off > 0; off >>= 1)
            sq += __shfl_xor(sq, off, 64);
        if (lane == 0) atomicAdd(&s_red, sq);
    }

    // ---------- vectorized full-slab stream ----------
    // Group g = 196 floats = 49 float4. Lane l<49 loads float4 (49g + l);
    // its elements j have FIXED position (4l+j) mod 49 for every g.
    // Wave w handles g = w, w+16, ..., w+240 (16 groups), unrolled x4.
    const bool  act = lane < PLANE;
    const float m   = act ? 1.0f : 0.0f;
    const int   lc  = act ? lane : 0;    // clamp inactive lanes to a safe addr
    float a0 = 0.0f, a1 = 0.0f, a2 = 0.0f, a3 = 0.0f;

    const float4* base = ob4 + (size_t)PLANE * w + lc;
    for (int i = 0; i < 16; i += 4) {
        float4 v0 = base[(size_t)PLANE * NWAVE * (i + 0)];
        float4 v1 = base[(size_t)PLANE * NWAVE * (i + 1)];
        float4 v2 = base[(size_t)PLANE * NWAVE * (i + 2)];
        float4 v3 = base[(size_t)PLANE * NWAVE * (i + 3)];
        a0 += m * __expf(v0.x); a1 += m * __expf(v0.y);
        a2 += m * __expf(v0.z); a3 += m * __expf(v0.w);
        a0 += m * __expf(v1.x); a1 += m * __expf(v1.y);
        a2 += m * __expf(v1.z); a3 += m * __expf(v1.w);
        a0 += m * __expf(v2.x); a1 += m * __expf(v2.y);
        a2 += m * __expf(v2.z); a3 += m * __expf(v2.w);
        a0 += m * __expf(v3.x); a1 += m * __expf(v3.y);
        a2 += m * __expf(v3.z); a3 += m * __expf(v3.w);
    }
    if (act) {
        float4* dst = (float4*)&s_slot[w][4 * lc];   // 16B-aligned
        *dst = make_float4(a0, a1, a2, a3);
    }
    __syncthreads();

    // ---------- fold 16x196 slot partials -> 49 positions; subtract rows 0..4 ----------
    if (w == 0 && lane < PLANE) {
        float s = 0.0f;
#pragma unroll
        for (int ww = 0; ww < NWAVE; ++ww) {
#pragma unroll
            for (int k = 0; k < 4; ++k)
                s += s_slot[ww][lane + PLANE * k];   // slots {p, p+49, p+98, p+147}
        }
        float corr = 0.0f;   // exp contribution of obj+bb rows (cache-hot reloads)
#pragma unroll
        for (int r = 0; r < 5; ++r)
            corr += __expf(ob[r * PLANE + lane]);
        s_sum[lane] = s - corr;
    }
    __syncthreads();

    // ---------- class CE (wave 0, lanes 0..15) ----------
    if (w == 0 && lane < NOBJ) {
        float se = s_sum[s_pos[lane]];
        float tl = ob[(size_t)(5 + s_cl[lane]) * PLANE + s_pos[lane]];  // cache hit
        float ce = __logf(se) - tl;
        atomicAdd(&s_red, ce);
    }
    __syncthreads();

    if (t == 0) atomicAdd(out, s_red * (1.0f / (float)BATCH));
}

extern "C" void kernel_launch(void* const* d_in, const int* in_sizes, int n_in,
                              void* d_out, int out_size, void* d_ws, size_t ws_size,
                              hipStream_t stream) {
    const float* outputs    = (const float*)d_in[0];
    const float* boxes      = (const float*)d_in[1];
    const int*   labels     = (const int*)d_in[2];
    const int*   coords     = (const int*)d_in[3];
    const float* obj_matrix = (const float*)d_in[4];
    float* out = (float*)d_out;

    hipMemsetAsync(out, 0, sizeof(float), stream);
    yolo_loss_kernel<<<BATCH, TPB, 0, stream>>>(outputs, boxes, labels, coords,
                                                obj_matrix, out);
}

// Round 5
// 91.846 us; speedup vs baseline: 1.6135x; 1.0148x over previous
//
#include <hip/hip_runtime.h>

#define BATCH 256
#define NCLS  1019
#define GRID  7
#define NOBJ  16
#define PLANE 49              // GRID*GRID
#define NCH   1024            // 5 + NCLS
#define SLAB  (NCH * PLANE)   // 50176 floats per batch = 196*256
#define TPB   1024
#define NWAVE 16
#define NGRP  16              // groups per wave (256 groups / 16 waves)

__global__ __launch_bounds__(TPB) void yolo_loss_kernel(
    const float* __restrict__ outputs,    // [B, 1024, 7, 7]
    const float* __restrict__ boxes,      // [B, 16, 4]
    const int*   __restrict__ labels,     // [B, 16]  (1..C)
    const int*   __restrict__ coords,     // [B, 16, 2] (x, y)
    const float* __restrict__ obj_matrix, // [B, 49]
    float* __restrict__ out)              // [1]
{
    const int b    = blockIdx.x;
    const int t    = threadIdx.x;
    const int lane = t & 63;
    const int w    = t >> 6;

    __shared__ float s_slot[NWAVE][4 * PLANE];  // 196 slot-partials per wave
    __shared__ float s_sum[PLANE];              // final per-position sumexp (class rows)
    __shared__ int   s_pos[NOBJ];
    __shared__ int   s_cl[NOBJ];
    __shared__ float s_red;

    const float*  ob  = outputs + (size_t)b * SLAB;
    const float4* ob4 = (const float4*)ob;      // slab base is 16B-aligned

    if (t == 0) s_red = 0.0f;
    if (t < NOBJ) {
        int x = coords[(b * NOBJ + t) * 2 + 0];
        int y = coords[(b * NOBJ + t) * 2 + 1];
        s_pos[t] = y * GRID + x;
        s_cl[t]  = labels[b * NOBJ + t] - 1;
    }
    __syncthreads();

    // ---------- objectness CE (wave 1) ----------
    if (w == 1) {
        float l = (lane < PLANE) ? ob[lane] : 0.0f;
        float s = (lane < PLANE) ? __expf(l) : 0.0f;
#pragma unroll
        for (int off = 32; off > 0; off >>= 1)
            s += __shfl_xor(s, off, 64);
        float lse = __logf(s);
        float mm = (lane < PLANE) ? obj_matrix[b * PLANE + lane] : 0.0f;
        float contrib = (lane < PLANE) ? -mm * (l - lse) : 0.0f;
#pragma unroll
        for (int off = 32; off > 0; off >>= 1)
            contrib += __shfl_xor(contrib, off, 64);
        if (lane == 0) atomicAdd(&s_red, contrib);
    }

    // ---------- bb MSE (wave 2) ----------
    if (w == 2) {
        int o = lane >> 2, k = lane & 3;   // 64 lanes = 16 objects x 4 coords
        float pred = ob[(size_t)(1 + k) * PLANE + s_pos[o]];
        float tb   = boxes[(b * NOBJ + o) * 4 + k];
        float tgt  = rintf(tb * (10.0f / 448.0f)) * 0.1f;  // round-half-even
        float d    = tgt - pred;
        float sq   = d * d;
#pragma unroll
        for (int off = 32; off > 0; off >>= 1)
            sq += __shfl_xor(sq, off, 64);
        if (lane == 0) atomicAdd(&s_red, sq);
    }

    // ---------- vectorized full-slab stream, deep ILP ----------
    // Group g = 196 floats = 49 float4. Lane l<49 loads float4 (49g + l);
    // element j of that float4 has FIXED position (4l+j) mod 49 for every g.
    // Wave w owns groups w, w+16, ..., w+240. All 16 loads issued up front.
    const bool act = lane < PLANE;
    const int  lc  = act ? lane : 0;     // clamp inactive lanes to a safe addr

    const float4* base = ob4 + (size_t)PLANE * w + lc;
    float4 v[NGRP];
#pragma unroll
    for (int i = 0; i < NGRP; ++i)
        v[i] = base[(size_t)PLANE * NWAVE * i];   // 16 loads in flight

    float a0 = 0.0f, a1 = 0.0f, a2 = 0.0f, a3 = 0.0f;
#pragma unroll
    for (int i = 0; i < NGRP; ++i) {
        a0 += __expf(v[i].x);
        a1 += __expf(v[i].y);
        a2 += __expf(v[i].z);
        a3 += __expf(v[i].w);
    }
    if (act) {
        float4* dst = (float4*)&s_slot[w][4 * lc];   // 16B-aligned
        *dst = make_float4(a0, a1, a2, a3);
    }
    __syncthreads();

    // ---------- fold 16x196 slot partials -> 49 positions; subtract rows 0..4 ----------
    if (w == 0 && lane < PLANE) {
        float s = 0.0f;
#pragma unroll
        for (int ww = 0; ww < NWAVE; ++ww) {
#pragma unroll
            for (int k = 0; k < 4; ++k)
                s += s_slot[ww][lane + PLANE * k];   // slots {p, p+49, p+98, p+147}
        }
        float corr = 0.0f;   // exp contribution of obj+bb rows (cache-hot reloads)
#pragma unroll
        for (int r = 0; r < 5; ++r)
            corr += __expf(ob[r * PLANE + lane]);
        s_sum[lane] = s - corr;
    }
    __syncthreads();

    // ---------- class CE (wave 0, lanes 0..15) ----------
    if (w == 0 && lane < NOBJ) {
        float se = s_sum[s_pos[lane]];
        float tl = ob[(size_t)(5 + s_cl[lane]) * PLANE + s_pos[lane]];  // cache hit
        float ce = __logf(se) - tl;
        atomicAdd(&s_red, ce);
    }
    __syncthreads();

    if (t == 0) atomicAdd(out, s_red * (1.0f / (float)BATCH));
}

extern "C" void kernel_launch(void* const* d_in, const int* in_sizes, int n_in,
                              void* d_out, int out_size, void* d_ws, size_t ws_size,
                              hipStream_t stream) {
    const float* outputs    = (const float*)d_in[0];
    const float* boxes      = (const float*)d_in[1];
    const int*   labels     = (const int*)d_in[2];
    const int*   coords     = (const int*)d_in[3];
    const float* obj_matrix = (const float*)d_in[4];
    float* out = (float*)d_out;

    hipMemsetAsync(out, 0, sizeof(float), stream);
    yolo_loss_kernel<<<BATCH, TPB, 0, stream>>>(outputs, boxes, labels, coords,
                                                obj_matrix, out);
}